// Round 15
// baseline (70.560 us; speedup 1.0000x reference)
//
#include <hip/hip_runtime.h>
#include <hip/hip_bf16.h>

// MSA: B=8, S=1024, H=16, D=64.
// K1: K/V projection, NO LDS transpose: K^T = mfma32(Wk, x^T) and
//     V = mfma32(x, Wv^T); C/D -> frags in registers via pack_cd
//     (cvt_pk+permlane32), direct 16B frag-order global stores. ONE barrier.
// K2: flash attention (R14, proven): 8 waves, QBLK=256, KVBLK=64,
//     reg-staged LDS dbuf, lgkm-only barriers, swapped QK^T, no-max
//     softmax, cvt_pk+permlane P-pack, LDS-staged on-the-fly Q.

typedef __attribute__((ext_vector_type(8))) short short8;
typedef __attribute__((ext_vector_type(4))) float f32x4;
typedef __attribute__((ext_vector_type(16))) float f32x16;
typedef __attribute__((ext_vector_type(2))) unsigned int u32x2;
typedef __attribute__((ext_vector_type(4))) unsigned int u32x4;

#define MFMA16 __builtin_amdgcn_mfma_f32_16x16x32_bf16
#define MFMA32 __builtin_amdgcn_mfma_f32_32x32x16_bf16

// log2(e) / sqrt(64)
#define QSCALE 0.1803368801111204f

__device__ __forceinline__ unsigned cvt_pk(float lo, float hi) {
  unsigned r;
  asm("v_cvt_pk_bf16_f32 %0, %1, %2" : "=v"(r) : "v"(lo), "v"(hi));
  return r;
}
__device__ __forceinline__ void pl32_swap(unsigned &a, unsigned &b) {
  asm("v_permlane32_swap_b32 %0, %1" : "+v"(a), "+v"(b));
}
__device__ __forceinline__ u32x2 pk4(const f32x4 v) {
  return (u32x2){cvt_pk(v[0], v[1]), cvt_pk(v[2], v[3])};
}
// C/D f32x16 (row of reg r = (r&3)+8*(r>>2)+4*hi) -> two frags:
// lo holds rows hi*8+j, hi8 holds rows 16+hi*8+j (j=0..7), col = lane&31.
__device__ __forceinline__ void pack_cd(const f32x16& p, short8& lo, short8& hi8) {
  unsigned d0 = cvt_pk(p[0],  p[1]);
  unsigned d2 = cvt_pk(p[4],  p[5]);
  pl32_swap(d0, d2);
  unsigned d1 = cvt_pk(p[2],  p[3]);
  unsigned d3 = cvt_pk(p[6],  p[7]);
  pl32_swap(d1, d3);
  u32x4 a = {d0, d1, d2, d3};
  unsigned e0 = cvt_pk(p[8],  p[9]);
  unsigned e2 = cvt_pk(p[12], p[13]);
  pl32_swap(e0, e2);
  unsigned e1 = cvt_pk(p[10], p[11]);
  unsigned e3 = cvt_pk(p[14], p[15]);
  pl32_swap(e1, e3);
  u32x4 b = {e0, e1, e2, e3};
  lo  = __builtin_bit_cast(short8, a);
  hi8 = __builtin_bit_cast(short8, b);
}
// barrier draining LDS ops only (global loads stay in flight)
__device__ __forceinline__ void lds_barrier() {
  asm volatile("s_waitcnt lgkmcnt(0)" ::: "memory");
  __builtin_amdgcn_s_barrier();
}

// ---------------- K1: K/V projection, transpose-free ----------------
// grid: (B*S/64) * H = 2048 blocks, 256 threads. Block (tb, h).
// kv_ws element addressing (u16), per bh (131072) per 64-tile (8192):
//   K elem (kl,d):  [(d>>4)*128 + (kl>>5)*64 + ((d>>3)&1)*32 + (kl&31)]*8 + (d&7)
//   V elem (kl,d):  4096 + [(kl>>4)*128 + (d>>5)*64 + ((kl>>3)&1)*32 + (d&31)]*8 + (kl&7)
__global__ __launch_bounds__(256) void kv_proj_kernel(
    const float* __restrict__ x,
    const float* __restrict__ Wk, const float* __restrict__ bk,
    const float* __restrict__ Wv, const float* __restrict__ bv,
    unsigned short* __restrict__ kv_ws)
{
  __shared__ unsigned short x_lds[64][72];
  __shared__ unsigned short w_lds[2][64][72];

  const int h   = blockIdx.x & 15;
  const int tb  = blockIdx.x >> 4;
  const int tid = threadIdx.x;
  const int w   = tid >> 6;
  const int l   = tid & 63;
  const int hi  = l >> 5;
  const int cc  = l & 31;

  { // stage x + Wk + Wv as bf16 (coalesced f32 loads, cvt_pk)
    const int i  = tid >> 2;
    const int q4 = tid & 3;
    const float* xs  = x  + (size_t)(tb * 64 + i) * 1024 + h * 64 + q4 * 16;
    const float* wsk = Wk + (size_t)h * 4096 + i * 64 + q4 * 16;
    const float* wsv = Wv + (size_t)h * 4096 + i * 64 + q4 * 16;
#pragma unroll
    for (int it = 0; it < 4; ++it) {
      const int c = q4 * 16 + it * 4;
      *(u32x2*)&x_lds[i][c]    = pk4(*(const f32x4*)(xs  + it * 4));
      *(u32x2*)&w_lds[0][i][c] = pk4(*(const f32x4*)(wsk + it * 4));
      *(u32x2*)&w_lds[1][i][c] = pk4(*(const f32x4*)(wsv + it * 4));
    }
  }
  __syncthreads();   // the ONLY barrier

  const int b = tb >> 4;
  unsigned short* kvt = kv_ws + (size_t)(b * 16 + h) * 131072
                              + (size_t)(tb & 15) * 8192;

  // ---- K^T tile (eb = w>>1, cb = w&1): C/D col = key, row = e ----
  {
    const int eb = w >> 1, cb = w & 1;
    f32x16 kkT = {};
#pragma unroll
    for (int ks = 0; ks < 4; ++ks) {
      short8 aW = *(const short8*)&w_lds[0][eb * 32 + cc][ks * 16 + hi * 8];
      short8 bX = *(const short8*)&x_lds[cb * 32 + cc][ks * 16 + hi * 8];
      kkT = MFMA32(aW, bX, kkT, 0, 0, 0);
    }
    // bias: e = eb*32 + (r&3) + 8*(r>>2) + 4*hi
    const float* bkb = bk + h * 64 + eb * 32 + 4 * hi;
    f32x4 bk0 = *(const f32x4*)(bkb);
    f32x4 bk1 = *(const f32x4*)(bkb + 8);
    f32x4 bk2 = *(const f32x4*)(bkb + 16);
    f32x4 bk3 = *(const f32x4*)(bkb + 24);
#pragma unroll
    for (int r = 0; r < 16; ++r) {
      const float bb = (r >> 2) == 0 ? bk0[r & 3] :
                       (r >> 2) == 1 ? bk1[r & 3] :
                       (r >> 2) == 2 ? bk2[r & 3] : bk3[r & 3];
      kkT[r] += bb;
    }
    short8 klo, khi;
    pack_cd(kkT, klo, khi);          // klo: d = eb*32+hi*8+j; khi: +16
    const int slot = 256 * eb + 64 * cb + 32 * hi + cc;
    *(short8*)&kvt[slot * 8]         = klo;
    *(short8*)&kvt[(slot + 128) * 8] = khi;
  }

  // ---- V tile (tb32 = w>>1, db = w&1): C/D col = d, row = key ----
  {
    const int tb32 = w >> 1, db = w & 1;
    f32x16 vvC = {};
#pragma unroll
    for (int ks = 0; ks < 4; ++ks) {
      short8 aX = *(const short8*)&x_lds[tb32 * 32 + cc][ks * 16 + hi * 8];
      short8 bW = *(const short8*)&w_lds[1][db * 32 + cc][ks * 16 + hi * 8];
      vvC = MFMA32(aX, bW, vvC, 0, 0, 0);
    }
    const float bvv = bv[h * 64 + db * 32 + cc];   // col = e = db*32+cc
#pragma unroll
    for (int r = 0; r < 16; ++r) vvC[r] += bvv;
    short8 vlo, vhi;
    pack_cd(vvC, vlo, vhi);          // vlo: kl = tb32*32+hi*8+j; vhi: +16
    const int slot = 256 * tb32 + 64 * db + 32 * hi + cc;
    *(short8*)&kvt[4096 + slot * 8]         = vlo;
    *(short8*)&kvt[4096 + (slot + 128) * 8] = vhi;
  }
}

// ---------------- K2: flash attention (R14, unchanged) ----------------
// grid: B*H*(S/256) = 512 blocks, 512 threads = 8 waves; QBLK=32/wave.
__global__ __launch_bounds__(512, 4) void attn_kernel(
    const float* __restrict__ x,
    const float* __restrict__ Wq, const float* __restrict__ bq,
    const unsigned short* __restrict__ kv_ws,
    float* __restrict__ out)
{
  __shared__ __align__(16) char lds[32768];   // main loop: 2 x [K 8KB | V 8KB]

  // XCD-bijective swizzle: 512 blocks = 8 XCDs x 64
  const int logical = (blockIdx.x & 7) * 64 + (blockIdx.x >> 3);
  const int qt = logical & 3;
  const int bh = logical >> 2;
  const int b  = bh >> 4;
  const int h  = bh & 15;
  const unsigned short* kvb = kv_ws + (size_t)bh * 131072;

  const int tid = threadIdx.x;
  const int w   = tid >> 6;
  const int l   = tid & 63;
  const int hi  = l >> 5;
  const int cc  = l & 31;

  // staging pointers (K/V main loop)
  const unsigned short* sgp = kvb + tid * 8;   // + t*8192 + j*4096 (u16)
  char* wbp = lds + tid * 16;                  // + buf*16384 + j*8192 (bytes)

  // issue K/V tile-0 loads first (latency hides under Q-proj below)
  short8 st[2];
#pragma unroll
  for (int j = 0; j < 2; ++j) st[j] = *(const short8*)(sgp + j * 4096);

  // ---- Q-projection prologue, LDS-staged, coalesced ----
  unsigned short* wq_l = (unsigned short*)lds;            // [64][72]
  unsigned short* xh_l = (unsigned short*)(lds + 9216);   // [128][72]

  { // stage Wq once: thread t -> row r=t>>3, seg s=t&7 (8 f32)
    const int r = tid >> 3, s = tid & 7;
    const float* ws = Wq + h * 4096 + r * 64 + s * 8;
    f32x4 v0 = *(const f32x4*)ws;
    f32x4 v1 = *(const f32x4*)(ws + 4);
    u32x4 d = {cvt_pk(v0[0], v0[1]), cvt_pk(v0[2], v0[3]),
               cvt_pk(v1[0], v1[1]), cvt_pk(v1[2], v1[3])};
    *(u32x4*)&wq_l[r * 72 + s * 8] = d;
  }

  short8 qf[4];
  f32x16 qa0 = {}, qa1 = {};
#pragma unroll
  for (int p = 0; p < 2; ++p) {
    { // stage x half p: thread t -> row r=t>>2 (of 128), seg s=t&3 (16 f32)
      const int r = tid >> 2, s = tid & 3;
      const float* xs = x + ((size_t)(b * 1024 + qt * 256 + p * 128 + r)) * 1024
                          + h * 64 + s * 16;
      f32x4 v0 = *(const f32x4*)xs;
      f32x4 v1 = *(const f32x4*)(xs + 4);
      f32x4 v2 = *(const f32x4*)(xs + 8);
      f32x4 v3 = *(const f32x4*)(xs + 12);
      u32x4 d0 = {cvt_pk(v0[0], v0[1]), cvt_pk(v0[2], v0[3]),
                  cvt_pk(v1[0], v1[1]), cvt_pk(v1[2], v1[3])};
      u32x4 d1 = {cvt_pk(v2[0], v2[1]), cvt_pk(v2[2], v2[3]),
                  cvt_pk(v3[0], v3[1]), cvt_pk(v3[2], v3[3])};
      *(u32x4*)&xh_l[r * 72 + s * 16]     = d0;
      *(u32x4*)&xh_l[r * 72 + s * 16 + 8] = d1;
    }
    lds_barrier();
    if ((w >> 2) == p) {
      const int tl = (w & 3) * 32 + cc;
#pragma unroll
      for (int c = 0; c < 4; ++c) {
        short8 xf  = *(const short8*)&xh_l[tl * 72 + c * 16 + hi * 8];
        short8 alo = *(const short8*)&wq_l[cc * 72 + c * 16 + hi * 8];
        short8 ahi = *(const short8*)&wq_l[(32 + cc) * 72 + c * 16 + hi * 8];
        qa0 = MFMA32(alo, xf, qa0, 0, 0, 0);
        qa1 = MFMA32(ahi, xf, qa1, 0, 0, 0);
      }
    }
    lds_barrier();
  }
  {
#pragma unroll
    for (int r = 0; r < 16; ++r) {
      const int e = (r & 3) + 8 * (r >> 2) + 4 * hi;
      qa0[r] = (qa0[r] + bq[h * 64 + e]) * QSCALE;
      qa1[r] = (qa1[r] + bq[h * 64 + 32 + e]) * QSCALE;
    }
    pack_cd(qa0, qf[0], qf[1]);
    pack_cd(qa1, qf[2], qf[3]);
  }

  // ---- K/V staging prologue ----
#pragma unroll
  for (int j = 0; j < 2; ++j) *(short8*)(wbp + j * 8192) = st[j];
#pragma unroll
  for (int j = 0; j < 2; ++j) st[j] = *(const short8*)(sgp + 8192 + j * 4096);
  lds_barrier();

  f32x16 ot0 = {}; f32x16 ot1 = {};
  float lsum = 0.f;

  for (int kv = 0; kv < 16; ++kv) {
    if (kv < 15) {
      char* d = wbp + ((kv + 1) & 1) * 16384;
#pragma unroll
      for (int j = 0; j < 2; ++j) *(short8*)(d + j * 8192) = st[j];
      if (kv < 14) {
        const unsigned short* s = sgp + (size_t)(kv + 2) * 8192;
#pragma unroll
        for (int j = 0; j < 2; ++j) st[j] = *(const short8*)(s + j * 4096);
      }
    }
    const char* kb_ = lds + (kv & 1) * 16384;
    const char* vb_ = kb_ + 8192;

    // ---- S^T = K Q^T ----
    f32x16 s0 = {}; f32x16 s1 = {};
    __builtin_amdgcn_s_setprio(1);
#pragma unroll
    for (int c = 0; c < 4; ++c) {
      s0 = MFMA32(*(const short8*)(kb_ + (c * 128 + l) * 16),      qf[c], s0, 0, 0, 0);
      s1 = MFMA32(*(const short8*)(kb_ + (c * 128 + 64 + l) * 16), qf[c], s1, 0, 0, 0);
    }
    __builtin_amdgcn_s_setprio(0);

    // ---- no-max softmax ----
    float ps0 = 0.f, ps1 = 0.f;
#pragma unroll
    for (int i = 0; i < 16; ++i) { s0[i] = __builtin_amdgcn_exp2f(s0[i]); ps0 += s0[i]; }
#pragma unroll
    for (int i = 0; i < 16; ++i) { s1[i] = __builtin_amdgcn_exp2f(s1[i]); ps1 += s1[i]; }
    lsum += ps0 + ps1;

    // ---- pack P^T, PV ----
#pragma unroll
    for (int kb = 0; kb < 2; ++kb) {
      short8 pa0, pa1;
      pack_cd(kb ? s1 : s0, pa0, pa1);

      const int c20 = kb * 2, c21 = kb * 2 + 1;
      __builtin_amdgcn_s_setprio(1);
      ot0 = MFMA32(*(const short8*)(vb_ + (c20 * 128 + l) * 16),      pa0, ot0, 0, 0, 0);
      ot1 = MFMA32(*(const short8*)(vb_ + (c20 * 128 + 64 + l) * 16), pa0, ot1, 0, 0, 0);
      ot0 = MFMA32(*(const short8*)(vb_ + (c21 * 128 + l) * 16),      pa1, ot0, 0, 0, 0);
      ot1 = MFMA32(*(const short8*)(vb_ + (c21 * 128 + 64 + l) * 16), pa1, ot1, 0, 0, 0);
      __builtin_amdgcn_s_setprio(0);
    }
    lds_barrier();
  }

  // ---- normalize + store ----
  const float lt  = lsum + __shfl_xor(lsum, 32, 64);
  const float inv = 1.0f / lt;
  const int s_row = qt * 256 + w * 32 + cc;
  float* op = out + ((size_t)(b * 1024 + s_row) << 10) + h * 64;
#pragma unroll
  for (int rg = 0; rg < 4; ++rg) {
    const int d0 = 8 * rg + 4 * hi;
    f32x4 v0, v1;
#pragma unroll
    for (int j = 0; j < 4; ++j) {
      v0[j] = ot0[rg * 4 + j] * inv;
      v1[j] = ot1[rg * 4 + j] * inv;
    }
    *(f32x4*)(op + d0)      = v0;
    *(f32x4*)(op + 32 + d0) = v1;
  }
}

extern "C" void kernel_launch(void* const* d_in, const int* in_sizes, int n_in,
                              void* d_out, int out_size, void* d_ws, size_t ws_size,
                              hipStream_t stream) {
  const float* x  = (const float*)d_in[0];
  const float* Wq = (const float*)d_in[1];
  const float* bq = (const float*)d_in[2];
  const float* Wk = (const float*)d_in[3];
  const float* bk = (const float*)d_in[4];
  const float* Wv = (const float*)d_in[5];
  const float* bv = (const float*)d_in[6];
  float* out = (float*)d_out;

  unsigned short* kv_ws = (unsigned short*)d_ws;   // 33.5 MB

  kv_proj_kernel<<<2048, 256, 0, stream>>>(x, Wk, bk, Wv, bv, kv_ws);
  attn_kernel<<<512, 512, 0, stream>>>(x, Wq, bq, kv_ws, out);
}